// Round 1
// baseline (103.099 us; speedup 1.0000x reference)
//
#include <hip/hip_runtime.h>

#define NN 1000
#define BB 8

// ws layout (floats):
//   rec [NN][12] : {Aj0,Aj1,Aj2,pad, x[b=0..7][j]}   offset 0
//   Ai  [NN][4]  : {Ai0+bf2e0, Ai1+bf2e1, Ai2+bf2e2, pad} offset 12*NN
//   XsT [NN]     : sum_b x[b,j]                       offset 16*NN
//   cst [32]     : uA[6], cB[6], vA[6], Wf2v[3], bf2v offset 17*NN

__device__ __forceinline__ float wave_sum(float v) {
#pragma unroll
    for (int o = 32; o > 0; o >>= 1) v += __shfl_xor(v, o, 64);
    return v;
}

__global__ void prep_kernel(const float* __restrict__ x,
                            const float* __restrict__ W1, const float* __restrict__ b1,
                            const float* __restrict__ W2, const float* __restrict__ b2,
                            const float* __restrict__ Wf1e, const float* __restrict__ bf1e,
                            const float* __restrict__ Wf2e, const float* __restrict__ bf2e,
                            const float* __restrict__ Wfk, const float* __restrict__ bfk,
                            const float* __restrict__ Wf1v, const float* __restrict__ bf1v,
                            const float* __restrict__ Wf2v, const float* __restrict__ bf2v,
                            float* __restrict__ ws) {
    float* rec = ws;            // [NN][12]
    float* Ai  = ws + 12 * NN;  // [NN][4]
    float* XsT = ws + 16 * NN;  // [NN]
    float* cst = ws + 17 * NN;  // [32]
    const int tid = threadIdx.x;

    __shared__ float s_part[4][8];
    __shared__ float s_small[6];

    // Phase 1: transpose x into rec, per-node batch-sum Xs, per-batch sum Sx
    float sx[8] = {0, 0, 0, 0, 0, 0, 0, 0};
    for (int j = tid; j < NN; j += 256) {
        float xs = 0.f;
#pragma unroll
        for (int b = 0; b < 8; ++b) {
            float v = x[b * NN + j];
            rec[j * 12 + 4 + b] = v;
            sx[b] += v;
            xs += v;
        }
        XsT[j] = xs;
    }
#pragma unroll
    for (int b = 0; b < 8; ++b) {
        float v = wave_sum(sx[b]);
        if ((tid & 63) == 0) s_part[tid >> 6][b] = v;
    }
    __syncthreads();

    // Phase 2: tiny serial algebra on thread 0
    if (tid == 0) {
        float Sx[8];
#pragma unroll
        for (int b = 0; b < 8; ++b)
            Sx[b] = s_part[0][b] + s_part[1][b] + s_part[2][b] + s_part[3][b];

        // h[b,i,f] = alpha[f]*x[b,i] + beta[b,f]
        float alpha[2];
        for (int f = 0; f < 2; ++f) {
            float a = 0.f;
            for (int e = 0; e < 4; ++e) a += W1[e] * Wf1e[(2 * e) * 2 + f];
            alpha[f] = (float)NN * a;
        }
        // h2[b,i,v] = gamma[v]*x[b,i] + delta[b,v]
        float gamma[3];
        for (int v = 0; v < 3; ++v) {
            float g = 0.f;
            for (int f = 0; f < 2; ++f) g += alpha[f] * Wf1v[f * 3 + v];
            gamma[v] = g;
        }
        float Ds[3] = {0.f, 0.f, 0.f};  // Dsum[v] = sum_b delta[b,v]
        for (int b = 0; b < 8; ++b) {
            float S1e[4];
            for (int e = 0; e < 4; ++e) S1e[e] = Sx[b] * W1[e] + (float)NN * b1[e];
            float beta[2];
            for (int f = 0; f < 2; ++f) {
                float t = 0.f;
                for (int e = 0; e < 4; ++e) t += b1[e] * Wf1e[(2 * e) * 2 + f];
                t *= (float)NN;
                for (int e = 0; e < 4; ++e) t += S1e[e] * Wf1e[(2 * e + 1) * 2 + f];
                t += (float)NN * bf1e[f];
                beta[f] = t;
            }
            for (int v = 0; v < 3; ++v) {
                float d = bf1v[v];
                for (int f = 0; f < 2; ++f) d += beta[f] * Wf1v[f * 3 + v];
                Ds[v] += d;
            }
        }
        for (int v = 0; v < 3; ++v) { s_small[v] = gamma[v]; s_small[3 + v] = Ds[v]; }

        // Final-combine constants: U[b,i,m,k] = uA[m,k]*x[b,i] + uB[m,k]; V likewise
        for (int m = 0; m < 2; ++m)
            for (int k = 0; k < 3; ++k) {
                float uA = 0.f, uB = 0.f, vA = 0.f, vB = 0.f;
                for (int e = 0; e < 4; ++e) {
                    float wE = Wfk[k * 16 + (2 * e) * 2 + m];
                    float wO = Wfk[k * 16 + (2 * e + 1) * 2 + m];
                    uA += W2[e] * wE; uB += b2[e] * wE;
                    vA += W2[e] * wO; vB += b2[e] * wO;
                }
                cst[m * 3 + k]      = uA;
                cst[6 + m * 3 + k]  = uB + bfk[k * 2 + m] + vB;  // uB + b_fk + vB
                cst[12 + m * 3 + k] = vA;
            }
        cst[18] = Wf2v[0]; cst[19] = Wf2v[1]; cst[20] = Wf2v[2]; cst[21] = bf2v[0];
    }
    __syncthreads();

    // Phase 3: per-node logit halves Ai (with bias baked in) and Aj
    const float g0 = s_small[0], g1 = s_small[1], g2 = s_small[2];
    const float d0 = s_small[3], d1 = s_small[4], d2 = s_small[5];
    for (int j = tid; j < NN; j += 256) {
        float xs = XsT[j];
        float H0 = g0 * xs + d0, H1 = g1 * xs + d1, H2 = g2 * xs + d2;
#pragma unroll
        for (int k = 0; k < 3; ++k) {
            Ai[j * 4 + k]   = H0 * Wf2e[0 * 3 + k] + H1 * Wf2e[2 * 3 + k] + H2 * Wf2e[4 * 3 + k] + bf2e[k];
            rec[j * 12 + k] = H0 * Wf2e[1 * 3 + k] + H1 * Wf2e[3 * 3 + k] + H2 * Wf2e[5 * 3 + k];
        }
        Ai[j * 4 + 3] = 0.f;
        rec[j * 12 + 3] = 0.f;
    }
}

__global__ __launch_bounds__(64) void main_kernel(const float* __restrict__ ws,
                                                  float* __restrict__ out) {
    const float* rec = ws;
    const float* Ai  = ws + 12 * NN;
    const float* cst = ws + 17 * NN;
    const int i = blockIdx.x;
    const int t = threadIdx.x;

    const float4 aif = *reinterpret_cast<const float4*>(Ai + i * 4);
    const float ai0 = aif.x, ai1 = aif.y, ai2 = aif.z;

    float Q0 = 0.f, Q1 = 0.f, Q2 = 0.f;
    float R[8][3];
#pragma unroll
    for (int b = 0; b < 8; ++b)
#pragma unroll
        for (int k = 0; k < 3; ++k) R[b][k] = 0.f;

    for (int j = t; j < NN; j += 64) {
        const float4 a  = *reinterpret_cast<const float4*>(rec + j * 12);
        const float4 xA = *reinterpret_cast<const float4*>(rec + j * 12 + 4);
        const float4 xB = *reinterpret_cast<const float4*>(rec + j * 12 + 8);
        float l0 = ai0 + a.x, l1 = ai1 + a.y, l2 = ai2 + a.z;
        float mx = fmaxf(l0, fmaxf(l1, l2));
        float e0 = __expf(l0 - mx), e1 = __expf(l1 - mx), e2 = __expf(l2 - mx);
        float inv = 1.f / (e0 + e1 + e2);
        float p0 = e0 * inv, p1 = e1 * inv, p2 = e2 * inv;
        Q0 += p0; Q1 += p1; Q2 += p2;
        float xv[8] = {xA.x, xA.y, xA.z, xA.w, xB.x, xB.y, xB.z, xB.w};
#pragma unroll
        for (int b = 0; b < 8; ++b) {
            R[b][0] += p0 * xv[b];
            R[b][1] += p1 * xv[b];
            R[b][2] += p2 * xv[b];
        }
    }

    Q0 = wave_sum(Q0); Q1 = wave_sum(Q1); Q2 = wave_sum(Q2);
#pragma unroll
    for (int b = 0; b < 8; ++b) {
        R[b][0] = wave_sum(R[b][0]);
        R[b][1] = wave_sum(R[b][1]);
        R[b][2] = wave_sum(R[b][2]);
    }

    if (t == 0) {
        float uA[6], cB[6], vA[6];
#pragma unroll
        for (int q = 0; q < 6; ++q) { uA[q] = cst[q]; cB[q] = cst[6 + q]; vA[q] = cst[12 + q]; }
        float w0 = cst[18], w1 = cst[19], w2 = cst[20], bf = cst[21];
        float Q[3] = {Q0, Q1, Q2};
#pragma unroll
        for (int b = 0; b < 8; ++b) {
            float xi = rec[i * 12 + 4 + b];
            float ve[2];
#pragma unroll
            for (int m = 0; m < 2; ++m) {
                float s = 0.f;
#pragma unroll
                for (int k = 0; k < 3; ++k)
                    s += Q[k] * (uA[m * 3 + k] * xi + cB[m * 3 + k]) + vA[m * 3 + k] * R[b][k];
                ve[m] = s;
            }
            out[b * NN + i] = xi + ve[0] * w0 + ve[1] * w1 + xi * w2 + bf;
        }
    }
}

extern "C" void kernel_launch(void* const* d_in, const int* in_sizes, int n_in,
                              void* d_out, int out_size, void* d_ws, size_t ws_size,
                              hipStream_t stream) {
    const float* x    = (const float*)d_in[0];
    const float* W1   = (const float*)d_in[1];
    const float* b1   = (const float*)d_in[2];
    const float* W2   = (const float*)d_in[3];
    const float* b2   = (const float*)d_in[4];
    const float* Wf1e = (const float*)d_in[5];
    const float* bf1e = (const float*)d_in[6];
    const float* Wf2e = (const float*)d_in[7];
    const float* bf2e = (const float*)d_in[8];
    const float* Wfk  = (const float*)d_in[9];
    const float* bfk  = (const float*)d_in[10];
    const float* Wf1v = (const float*)d_in[11];
    const float* bf1v = (const float*)d_in[12];
    const float* Wf2v = (const float*)d_in[13];
    const float* bf2v = (const float*)d_in[14];
    float* ws = (float*)d_ws;

    prep_kernel<<<1, 256, 0, stream>>>(x, W1, b1, W2, b2, Wf1e, bf1e, Wf2e, bf2e,
                                       Wfk, bfk, Wf1v, bf1v, Wf2v, bf2v, ws);
    main_kernel<<<NN, 64, 0, stream>>>(ws, (float*)d_out);
}

// Round 2
// 100.896 us; speedup vs baseline: 1.0218x; 1.0218x over previous
//
#include <hip/hip_runtime.h>

#define NN 1000

__device__ __forceinline__ float wave_sum(float v) {
#pragma unroll
    for (int o = 32; o > 0; o >>= 1) v += __shfl_xor(v, o, 64);
    return v;
}

__global__ __launch_bounds__(256) void fused_kernel(
    const float* __restrict__ x,
    const float* __restrict__ W1, const float* __restrict__ b1,
    const float* __restrict__ W2, const float* __restrict__ b2,
    const float* __restrict__ Wf1e, const float* __restrict__ bf1e,
    const float* __restrict__ Wf2e, const float* __restrict__ bf2e,
    const float* __restrict__ Wfk, const float* __restrict__ bfk,
    const float* __restrict__ Wf1v, const float* __restrict__ bf1v,
    const float* __restrict__ Wf2v, const float* __restrict__ bf2v,
    float* __restrict__ out) {
    const int wave = threadIdx.x >> 6;
    const int lane = threadIdx.x & 63;
    const int i = blockIdx.x * 4 + wave;   // 250 blocks * 4 waves = 1000 rows

    // ---- Phase A: S = sum over ALL of x (each wave redundantly; 2000 float4) ----
    float s = 0.f;
    const float4* x4 = reinterpret_cast<const float4*>(x);
    for (int q = lane; q < 2 * NN; q += 64) {
        float4 v = x4[q];
        s += (v.x + v.y) + (v.z + v.w);
    }
    const float S = wave_sum(s);

    // ---- Wave-uniform constant algebra (weights are uniform -> scalar loads) ----
    // h[b,i,f]  = alpha[f]*x[b,i] + beta[b,f]
    float alpha[2];
#pragma unroll
    for (int f = 0; f < 2; ++f) {
        float a = 0.f;
#pragma unroll
        for (int e = 0; e < 4; ++e) a += W1[e] * Wf1e[(2 * e) * 2 + f];
        alpha[f] = (float)NN * a;
    }
    // h2[b,i,v] = gamma[v]*x[b,i] + delta[b,v];   Ds[v] = sum_b delta[b,v]
    float gamma[3];
#pragma unroll
    for (int v = 0; v < 3; ++v) {
        float g = 0.f;
#pragma unroll
        for (int f = 0; f < 2; ++f) g += alpha[f] * Wf1v[f * 3 + v];
        gamma[v] = g;
    }
    float Bsum[2];   // sum_b beta[b,f] — affine in S only
#pragma unroll
    for (int f = 0; f < 2; ++f) {
        float t0 = 0.f, t1 = 0.f;
#pragma unroll
        for (int e = 0; e < 4; ++e) {
            t0 += b1[e] * Wf1e[(2 * e) * 2 + f];
            t1 += (S * W1[e] + 8.f * (float)NN * b1[e]) * Wf1e[(2 * e + 1) * 2 + f];
        }
        Bsum[f] = 8.f * (float)NN * t0 + t1 + 8.f * (float)NN * bf1e[f];
    }
    float Ds[3];
#pragma unroll
    for (int v = 0; v < 3; ++v) {
        float d = 8.f * bf1v[v];
#pragma unroll
        for (int f = 0; f < 2; ++f) d += Bsum[f] * Wf1v[f * 3 + v];
        Ds[v] = d;
    }
    // edge_logits[i,j,k] = (PA[k]*Xs_i + QA[k] + QB[k]) + PB[k]*Xs_j
    float PB[3], AiQ[3];
    {
        // Xs_i = sum_b x[b,i] (wave-uniform)
        float xsi = 0.f;
#pragma unroll
        for (int b = 0; b < 8; ++b) xsi += x[b * NN + i];
#pragma unroll
        for (int k = 0; k < 3; ++k) {
            float PA = 0.f, QA = 0.f, pb = 0.f, qb = 0.f;
#pragma unroll
            for (int v = 0; v < 3; ++v) {
                PA += gamma[v] * Wf2e[(2 * v) * 3 + k];
                QA += Ds[v]    * Wf2e[(2 * v) * 3 + k];
                pb += gamma[v] * Wf2e[(2 * v + 1) * 3 + k];
                qb += Ds[v]    * Wf2e[(2 * v + 1) * 3 + k];
            }
            PB[k]  = pb;
            AiQ[k] = PA * xsi + QA + bf2e[k] + qb;
        }
    }
    // message-combine constants
    float uA[6], cB[6], vA[6];
#pragma unroll
    for (int m = 0; m < 2; ++m)
#pragma unroll
        for (int k = 0; k < 3; ++k) {
            float ua = 0.f, ub = 0.f, va = 0.f, vb = 0.f;
#pragma unroll
            for (int e = 0; e < 4; ++e) {
                float wE = Wfk[k * 16 + (2 * e) * 2 + m];
                float wO = Wfk[k * 16 + (2 * e + 1) * 2 + m];
                ua += W2[e] * wE; ub += b2[e] * wE;
                va += W2[e] * wO; vb += b2[e] * wO;
            }
            uA[m * 3 + k] = ua;
            cB[m * 3 + k] = ub + vb + bfk[k * 2 + m];
            vA[m * 3 + k] = va;
        }

    // ---- Phase B: j-loop (x is L1-resident after Phase A) ----
    const float ai0 = AiQ[0], ai1 = AiQ[1], ai2 = AiQ[2];
    const float pb0 = PB[0], pb1 = PB[1], pb2 = PB[2];
    float Q0 = 0.f, Q1 = 0.f, Q2 = 0.f;
    float R[8][3];
#pragma unroll
    for (int b = 0; b < 8; ++b)
#pragma unroll
        for (int k = 0; k < 3; ++k) R[b][k] = 0.f;

    for (int j = lane; j < NN; j += 64) {
        float xv[8], xs = 0.f;
#pragma unroll
        for (int b = 0; b < 8; ++b) { xv[b] = x[b * NN + j]; xs += xv[b]; }
        float l0 = ai0 + pb0 * xs, l1 = ai1 + pb1 * xs, l2 = ai2 + pb2 * xs;
        float mx = fmaxf(l0, fmaxf(l1, l2));
        float e0 = __expf(l0 - mx), e1 = __expf(l1 - mx), e2 = __expf(l2 - mx);
        float inv = 1.f / (e0 + e1 + e2);
        float p0 = e0 * inv, p1 = e1 * inv, p2 = e2 * inv;
        Q0 += p0; Q1 += p1; Q2 += p2;
#pragma unroll
        for (int b = 0; b < 8; ++b) {
            R[b][0] += p0 * xv[b];
            R[b][1] += p1 * xv[b];
            R[b][2] += p2 * xv[b];
        }
    }

    Q0 = wave_sum(Q0); Q1 = wave_sum(Q1); Q2 = wave_sum(Q2);
#pragma unroll
    for (int b = 0; b < 8; ++b) {
        R[b][0] = wave_sum(R[b][0]);
        R[b][1] = wave_sum(R[b][1]);
        R[b][2] = wave_sum(R[b][2]);
    }

    // ---- Epilogue: lanes 0..7 each write one batch row ----
    if (lane < 8) {
        const int b = lane;
        float xi = x[b * NN + i];
        float Rk0 = R[b][0], Rk1 = R[b][1], Rk2 = R[b][2];
        float ve[2];
#pragma unroll
        for (int m = 0; m < 2; ++m) {
            ve[m] = Q0 * (uA[m * 3 + 0] * xi + cB[m * 3 + 0]) + vA[m * 3 + 0] * Rk0
                  + Q1 * (uA[m * 3 + 1] * xi + cB[m * 3 + 1]) + vA[m * 3 + 1] * Rk1
                  + Q2 * (uA[m * 3 + 2] * xi + cB[m * 3 + 2]) + vA[m * 3 + 2] * Rk2;
        }
        out[b * NN + i] = xi + ve[0] * Wf2v[0] + ve[1] * Wf2v[1] + xi * Wf2v[2] + bf2v[0];
    }
}

extern "C" void kernel_launch(void* const* d_in, const int* in_sizes, int n_in,
                              void* d_out, int out_size, void* d_ws, size_t ws_size,
                              hipStream_t stream) {
    const float* x    = (const float*)d_in[0];
    const float* W1   = (const float*)d_in[1];
    const float* b1   = (const float*)d_in[2];
    const float* W2   = (const float*)d_in[3];
    const float* b2   = (const float*)d_in[4];
    const float* Wf1e = (const float*)d_in[5];
    const float* bf1e = (const float*)d_in[6];
    const float* Wf2e = (const float*)d_in[7];
    const float* bf2e = (const float*)d_in[8];
    const float* Wfk  = (const float*)d_in[9];
    const float* bfk  = (const float*)d_in[10];
    const float* Wf1v = (const float*)d_in[11];
    const float* bf1v = (const float*)d_in[12];
    const float* Wf2v = (const float*)d_in[13];
    const float* bf2v = (const float*)d_in[14];

    fused_kernel<<<NN / 4, 256, 0, stream>>>(x, W1, b1, W2, b2, Wf1e, bf1e,
                                             Wf2e, bf2e, Wfk, bfk, Wf1v, bf1v,
                                             Wf2v, bf2v, (float*)d_out);
}

// Round 3
// 97.509 us; speedup vs baseline: 1.0573x; 1.0347x over previous
//
#include <hip/hip_runtime.h>

#define NN 1000

__device__ __forceinline__ float wave_sum(float v) {
#pragma unroll
    for (int o = 32; o > 0; o >>= 1) v += __shfl_xor(v, o, 64);
    return v;
}

__global__ __launch_bounds__(256) void fused_kernel(
    const float* __restrict__ x,
    const float* __restrict__ W1, const float* __restrict__ b1,
    const float* __restrict__ W2, const float* __restrict__ b2,
    const float* __restrict__ Wf1e, const float* __restrict__ bf1e,
    const float* __restrict__ Wf2e, const float* __restrict__ bf2e,
    const float* __restrict__ Wfk, const float* __restrict__ bfk,
    const float* __restrict__ Wf1v, const float* __restrict__ bf1v,
    const float* __restrict__ Wf2v, const float* __restrict__ bf2v,
    float* __restrict__ out) {
    const int wave = threadIdx.x >> 6;
    const int lane = threadIdx.x & 63;
    const int i = blockIdx.x * 4 + wave;   // 250 blocks * 4 waves = 1000 rows

    __shared__ float sA[4];

    // ---- Phase A: block-cooperative S = sum over ALL of x (8 float4/thread) ----
    float s = 0.f;
    const float4* x4 = reinterpret_cast<const float4*>(x);
    for (int q = threadIdx.x; q < 2 * NN; q += 256) {
        float4 v = x4[q];
        s += (v.x + v.y) + (v.z + v.w);
    }
    s = wave_sum(s);
    if (lane == 0) sA[wave] = s;

    // ---- S-independent wave-uniform constants (overlap with LDS sync) ----
    // h[b,i,f]  = alpha[f]*x[b,i] + beta[b,f]
    float alpha[2];
#pragma unroll
    for (int f = 0; f < 2; ++f) {
        float a = 0.f;
#pragma unroll
        for (int e = 0; e < 4; ++e) a += W1[e] * Wf1e[(2 * e) * 2 + f];
        alpha[f] = (float)NN * a;
    }
    float gamma[3];
#pragma unroll
    for (int v = 0; v < 3; ++v) {
        float g = 0.f;
#pragma unroll
        for (int f = 0; f < 2; ++f) g += alpha[f] * Wf1v[f * 3 + v];
        gamma[v] = g;
    }
    // message-combine constants
    float uA[6], cB[6], vA[6];
#pragma unroll
    for (int m = 0; m < 2; ++m)
#pragma unroll
        for (int k = 0; k < 3; ++k) {
            float ua = 0.f, ub = 0.f, va = 0.f, vb = 0.f;
#pragma unroll
            for (int e = 0; e < 4; ++e) {
                float wE = Wfk[k * 16 + (2 * e) * 2 + m];
                float wO = Wfk[k * 16 + (2 * e + 1) * 2 + m];
                ua += W2[e] * wE; ub += b2[e] * wE;
                va += W2[e] * wO; vb += b2[e] * wO;
            }
            uA[m * 3 + k] = ua;
            cB[m * 3 + k] = ub + vb + bfk[k * 2 + m];
            vA[m * 3 + k] = va;
        }

    __syncthreads();
    const float S = (sA[0] + sA[1]) + (sA[2] + sA[3]);

    // ---- S-dependent constants ----
    float Bsum[2];   // sum_b beta[b,f] — affine in S only
#pragma unroll
    for (int f = 0; f < 2; ++f) {
        float t0 = 0.f, t1 = 0.f;
#pragma unroll
        for (int e = 0; e < 4; ++e) {
            t0 += b1[e] * Wf1e[(2 * e) * 2 + f];
            t1 += (S * W1[e] + 8.f * (float)NN * b1[e]) * Wf1e[(2 * e + 1) * 2 + f];
        }
        Bsum[f] = 8.f * (float)NN * t0 + t1 + 8.f * (float)NN * bf1e[f];
    }
    float Ds[3];
#pragma unroll
    for (int v = 0; v < 3; ++v) {
        float d = 8.f * bf1v[v];
#pragma unroll
        for (int f = 0; f < 2; ++f) d += Bsum[f] * Wf1v[f * 3 + v];
        Ds[v] = d;
    }
    // edge_logits[i,j,k] = AiQ[k] + PB[k]*Xs_j
    float PB[3], AiQ[3];
    {
        float xsi = 0.f;
#pragma unroll
        for (int b = 0; b < 8; ++b) xsi += x[b * NN + i];
#pragma unroll
        for (int k = 0; k < 3; ++k) {
            float PA = 0.f, QA = 0.f, pb = 0.f, qb = 0.f;
#pragma unroll
            for (int v = 0; v < 3; ++v) {
                PA += gamma[v] * Wf2e[(2 * v) * 3 + k];
                QA += Ds[v]    * Wf2e[(2 * v) * 3 + k];
                pb += gamma[v] * Wf2e[(2 * v + 1) * 3 + k];
                qb += Ds[v]    * Wf2e[(2 * v + 1) * 3 + k];
            }
            PB[k]  = pb;
            AiQ[k] = PA * xsi + QA + bf2e[k] + qb;
        }
    }

    // ---- Phase B: float4 j-loop (250 float4-columns, 4 iterations) ----
    const float ai0 = AiQ[0], ai1 = AiQ[1], ai2 = AiQ[2];
    const float pb0 = PB[0], pb1 = PB[1], pb2 = PB[2];
    float Q0 = 0.f, Q1 = 0.f, Q2 = 0.f;
    float R[8][3];
#pragma unroll
    for (int b = 0; b < 8; ++b)
#pragma unroll
        for (int k = 0; k < 3; ++k) R[b][k] = 0.f;

    for (int j4 = lane; j4 < NN / 4; j4 += 64) {
        float4 v[8];
#pragma unroll
        for (int b = 0; b < 8; ++b)
            v[b] = *reinterpret_cast<const float4*>(x + b * NN + 4 * j4);
        const float* vf = reinterpret_cast<const float*>(v);
#pragma unroll
        for (int u = 0; u < 4; ++u) {
            float xs = 0.f;
#pragma unroll
            for (int b = 0; b < 8; ++b) xs += vf[b * 4 + u];
            float l0 = ai0 + pb0 * xs, l1 = ai1 + pb1 * xs, l2 = ai2 + pb2 * xs;
            float mx = fmaxf(l0, fmaxf(l1, l2));
            float e0 = __expf(l0 - mx), e1 = __expf(l1 - mx), e2 = __expf(l2 - mx);
            float inv = 1.f / (e0 + e1 + e2);
            float p0 = e0 * inv, p1 = e1 * inv, p2 = e2 * inv;
            Q0 += p0; Q1 += p1; Q2 += p2;
#pragma unroll
            for (int b = 0; b < 8; ++b) {
                float xb = vf[b * 4 + u];
                R[b][0] += p0 * xb;
                R[b][1] += p1 * xb;
                R[b][2] += p2 * xb;
            }
        }
    }

    Q0 = wave_sum(Q0); Q1 = wave_sum(Q1); Q2 = wave_sum(Q2);
#pragma unroll
    for (int b = 0; b < 8; ++b) {
        R[b][0] = wave_sum(R[b][0]);
        R[b][1] = wave_sum(R[b][1]);
        R[b][2] = wave_sum(R[b][2]);
    }

    // ---- Epilogue: lanes 0..7 each write one batch row ----
    if (lane < 8) {
        const int b = lane;
        float xi = x[b * NN + i];
        float Rk0 = R[b][0], Rk1 = R[b][1], Rk2 = R[b][2];
        float ve[2];
#pragma unroll
        for (int m = 0; m < 2; ++m) {
            ve[m] = Q0 * (uA[m * 3 + 0] * xi + cB[m * 3 + 0]) + vA[m * 3 + 0] * Rk0
                  + Q1 * (uA[m * 3 + 1] * xi + cB[m * 3 + 1]) + vA[m * 3 + 1] * Rk1
                  + Q2 * (uA[m * 3 + 2] * xi + cB[m * 3 + 2]) + vA[m * 3 + 2] * Rk2;
        }
        out[b * NN + i] = xi + ve[0] * Wf2v[0] + ve[1] * Wf2v[1] + xi * Wf2v[2] + bf2v[0];
    }
}

extern "C" void kernel_launch(void* const* d_in, const int* in_sizes, int n_in,
                              void* d_out, int out_size, void* d_ws, size_t ws_size,
                              hipStream_t stream) {
    const float* x    = (const float*)d_in[0];
    const float* W1   = (const float*)d_in[1];
    const float* b1   = (const float*)d_in[2];
    const float* W2   = (const float*)d_in[3];
    const float* b2   = (const float*)d_in[4];
    const float* Wf1e = (const float*)d_in[5];
    const float* bf1e = (const float*)d_in[6];
    const float* Wf2e = (const float*)d_in[7];
    const float* bf2e = (const float*)d_in[8];
    const float* Wfk  = (const float*)d_in[9];
    const float* bfk  = (const float*)d_in[10];
    const float* Wf1v = (const float*)d_in[11];
    const float* bf1v = (const float*)d_in[12];
    const float* Wf2v = (const float*)d_in[13];
    const float* bf2v = (const float*)d_in[14];

    fused_kernel<<<NN / 4, 256, 0, stream>>>(x, W1, b1, W2, b2, Wf1e, bf1e,
                                             Wf2e, bf2e, Wfk, bfk, Wf1v, bf1v,
                                             Wf2v, bf2v, (float*)d_out);
}

// Round 4
// 93.943 us; speedup vs baseline: 1.0975x; 1.0380x over previous
//
#include <hip/hip_runtime.h>

#define NN 1000

__device__ __forceinline__ float wave_sum(float v) {
#pragma unroll
    for (int o = 32; o > 0; o >>= 1) v += __shfl_xor(v, o, 64);
    return v;
}

__global__ __launch_bounds__(256) void fused_kernel(
    const float* __restrict__ x,
    const float* __restrict__ W1, const float* __restrict__ b1,
    const float* __restrict__ W2, const float* __restrict__ b2,
    const float* __restrict__ Wf1e, const float* __restrict__ bf1e,
    const float* __restrict__ Wf2e, const float* __restrict__ bf2e,
    const float* __restrict__ Wfk, const float* __restrict__ bfk,
    const float* __restrict__ Wf1v, const float* __restrict__ bf1v,
    const float* __restrict__ Wf2v, const float* __restrict__ bf2v,
    float* __restrict__ out) {
    const int wave = threadIdx.x >> 6;
    const int lane = threadIdx.x & 63;
    const int i = blockIdx.x * 4 + wave;   // 250 blocks * 4 waves = 1000 rows

    // ---- Single load pass: all of x into registers (wave covers all 1000 j) ----
    // 250 float4-columns; lane covers j4 = lane + 64*t, t=0..3 (t=3 only if lane<58)
    float4 v[4][8];
#pragma unroll
    for (int t = 0; t < 4; ++t) {
        const int j4 = lane + 64 * t;
        if (j4 < NN / 4) {
#pragma unroll
            for (int b = 0; b < 8; ++b)
                v[t][b] = *reinterpret_cast<const float4*>(x + b * NN + 4 * j4);
        }
    }

    // ---- S = sum of all x, from registers ----
    float s = 0.f;
#pragma unroll
    for (int t = 0; t < 4; ++t) {
        if (lane + 64 * t < NN / 4) {
#pragma unroll
            for (int b = 0; b < 8; ++b)
                s += (v[t][b].x + v[t][b].y) + (v[t][b].z + v[t][b].w);
        }
    }
    const float S = wave_sum(s);

    // ---- Wave-uniform constant algebra ----
    float alpha[2];
#pragma unroll
    for (int f = 0; f < 2; ++f) {
        float a = 0.f;
#pragma unroll
        for (int e = 0; e < 4; ++e) a += W1[e] * Wf1e[(2 * e) * 2 + f];
        alpha[f] = (float)NN * a;
    }
    float gamma[3];
#pragma unroll
    for (int vv = 0; vv < 3; ++vv) {
        float g = 0.f;
#pragma unroll
        for (int f = 0; f < 2; ++f) g += alpha[f] * Wf1v[f * 3 + vv];
        gamma[vv] = g;
    }
    float uA[6], cB[6], vAc[6];
#pragma unroll
    for (int m = 0; m < 2; ++m)
#pragma unroll
        for (int k = 0; k < 3; ++k) {
            float ua = 0.f, ub = 0.f, va = 0.f, vb = 0.f;
#pragma unroll
            for (int e = 0; e < 4; ++e) {
                float wE = Wfk[k * 16 + (2 * e) * 2 + m];
                float wO = Wfk[k * 16 + (2 * e + 1) * 2 + m];
                ua += W2[e] * wE; ub += b2[e] * wE;
                va += W2[e] * wO; vb += b2[e] * wO;
            }
            uA[m * 3 + k]  = ua;
            cB[m * 3 + k]  = ub + vb + bfk[k * 2 + m];
            vAc[m * 3 + k] = va;
        }
    float Bsum[2];
#pragma unroll
    for (int f = 0; f < 2; ++f) {
        float t0 = 0.f, t1 = 0.f;
#pragma unroll
        for (int e = 0; e < 4; ++e) {
            t0 += b1[e] * Wf1e[(2 * e) * 2 + f];
            t1 += (S * W1[e] + 8.f * (float)NN * b1[e]) * Wf1e[(2 * e + 1) * 2 + f];
        }
        Bsum[f] = 8.f * (float)NN * t0 + t1 + 8.f * (float)NN * bf1e[f];
    }
    float Ds[3];
#pragma unroll
    for (int vv = 0; vv < 3; ++vv) {
        float d = 8.f * bf1v[vv];
#pragma unroll
        for (int f = 0; f < 2; ++f) d += Bsum[f] * Wf1v[f * 3 + vv];
        Ds[vv] = d;
    }
    float PB[3], AiQ[3];
    {
        float xsi = 0.f;
#pragma unroll
        for (int b = 0; b < 8; ++b) xsi += x[b * NN + i];
#pragma unroll
        for (int k = 0; k < 3; ++k) {
            float PA = 0.f, QA = 0.f, pb = 0.f, qb = 0.f;
#pragma unroll
            for (int vv = 0; vv < 3; ++vv) {
                PA += gamma[vv] * Wf2e[(2 * vv) * 3 + k];
                QA += Ds[vv]    * Wf2e[(2 * vv) * 3 + k];
                pb += gamma[vv] * Wf2e[(2 * vv + 1) * 3 + k];
                qb += Ds[vv]    * Wf2e[(2 * vv + 1) * 3 + k];
            }
            PB[k]  = pb;
            AiQ[k] = PA * xsi + QA + bf2e[k] + qb;
        }
    }

    // ---- Softmax + weighted sums, fully register-resident ----
    const float ai0 = AiQ[0], ai1 = AiQ[1], ai2 = AiQ[2];
    const float pb0 = PB[0], pb1 = PB[1], pb2 = PB[2];
    float Q0 = 0.f, Q1 = 0.f, Q2 = 0.f;
    float R[8][3];
#pragma unroll
    for (int b = 0; b < 8; ++b)
#pragma unroll
        for (int k = 0; k < 3; ++k) R[b][k] = 0.f;

#pragma unroll
    for (int t = 0; t < 4; ++t) {
        if (lane + 64 * t < NN / 4) {
            const float* vf = reinterpret_cast<const float*>(v[t]);
#pragma unroll
            for (int u = 0; u < 4; ++u) {
                float xs = 0.f;
#pragma unroll
                for (int b = 0; b < 8; ++b) xs += vf[b * 4 + u];
                float l0 = ai0 + pb0 * xs, l1 = ai1 + pb1 * xs, l2 = ai2 + pb2 * xs;
                float mx = fmaxf(l0, fmaxf(l1, l2));
                float e0 = __expf(l0 - mx), e1 = __expf(l1 - mx), e2 = __expf(l2 - mx);
                float inv = 1.f / (e0 + e1 + e2);
                float p0 = e0 * inv, p1 = e1 * inv, p2 = e2 * inv;
                Q0 += p0; Q1 += p1; Q2 += p2;
#pragma unroll
                for (int b = 0; b < 8; ++b) {
                    float xb = vf[b * 4 + u];
                    R[b][0] += p0 * xb;
                    R[b][1] += p1 * xb;
                    R[b][2] += p2 * xb;
                }
            }
        }
    }

    Q0 = wave_sum(Q0); Q1 = wave_sum(Q1); Q2 = wave_sum(Q2);
#pragma unroll
    for (int b = 0; b < 8; ++b) {
        R[b][0] = wave_sum(R[b][0]);
        R[b][1] = wave_sum(R[b][1]);
        R[b][2] = wave_sum(R[b][2]);
    }

    // ---- Epilogue: lanes 0..7 each write one batch row ----
    if (lane < 8) {
        const int b = lane;
        float xi = x[b * NN + i];
        float Rk0 = R[b][0], Rk1 = R[b][1], Rk2 = R[b][2];
        float ve[2];
#pragma unroll
        for (int m = 0; m < 2; ++m) {
            ve[m] = Q0 * (uA[m * 3 + 0] * xi + cB[m * 3 + 0]) + vAc[m * 3 + 0] * Rk0
                  + Q1 * (uA[m * 3 + 1] * xi + cB[m * 3 + 1]) + vAc[m * 3 + 1] * Rk1
                  + Q2 * (uA[m * 3 + 2] * xi + cB[m * 3 + 2]) + vAc[m * 3 + 2] * Rk2;
        }
        out[b * NN + i] = xi + ve[0] * Wf2v[0] + ve[1] * Wf2v[1] + xi * Wf2v[2] + bf2v[0];
    }
}

extern "C" void kernel_launch(void* const* d_in, const int* in_sizes, int n_in,
                              void* d_out, int out_size, void* d_ws, size_t ws_size,
                              hipStream_t stream) {
    const float* x    = (const float*)d_in[0];
    const float* W1   = (const float*)d_in[1];
    const float* b1   = (const float*)d_in[2];
    const float* W2   = (const float*)d_in[3];
    const float* b2   = (const float*)d_in[4];
    const float* Wf1e = (const float*)d_in[5];
    const float* bf1e = (const float*)d_in[6];
    const float* Wf2e = (const float*)d_in[7];
    const float* bf2e = (const float*)d_in[8];
    const float* Wfk  = (const float*)d_in[9];
    const float* bfk  = (const float*)d_in[10];
    const float* Wf1v = (const float*)d_in[11];
    const float* bf1v = (const float*)d_in[12];
    const float* Wf2v = (const float*)d_in[13];
    const float* bf2v = (const float*)d_in[14];

    fused_kernel<<<NN / 4, 256, 0, stream>>>(x, W1, b1, W2, b2, Wf1e, bf1e,
                                             Wf2e, bf2e, Wfk, bfk, Wf1v, bf1v,
                                             Wf2v, bf2v, (float*)d_out);
}

// Round 5
// 93.728 us; speedup vs baseline: 1.1000x; 1.0023x over previous
//
#include <hip/hip_runtime.h>

#define NN 1000

__device__ __forceinline__ float wave_sum(float v) {
#pragma unroll
    for (int o = 32; o > 0; o >>= 1) v += __shfl_xor(v, o, 64);
    return v;
}

__global__ __launch_bounds__(256) void fused_kernel(
    const float* __restrict__ x,
    const float* __restrict__ W1, const float* __restrict__ b1,
    const float* __restrict__ W2, const float* __restrict__ b2,
    const float* __restrict__ Wf1e, const float* __restrict__ bf1e,
    const float* __restrict__ Wf2e, const float* __restrict__ bf2e,
    const float* __restrict__ Wfk, const float* __restrict__ bfk,
    const float* __restrict__ Wf1v, const float* __restrict__ bf1v,
    const float* __restrict__ Wf2v, const float* __restrict__ bf2v,
    float* __restrict__ out) {
    const int wave = threadIdx.x >> 6;
    const int lane = threadIdx.x & 63;
    const int i = blockIdx.x * 4 + wave;   // 250 blocks * 4 waves = 1000 rows

    // ---- Single load pass: all of x into registers (wave covers all 1000 j) ----
    float4 v[4][8];
#pragma unroll
    for (int t = 0; t < 4; ++t) {
        const int j4 = lane + 64 * t;
        if (j4 < NN / 4) {
#pragma unroll
            for (int b = 0; b < 8; ++b)
                v[t][b] = *reinterpret_cast<const float4*>(x + b * NN + 4 * j4);
        }
    }

    // ---- Per-batch sums Xs_b (and S = sum_b Xs_b), from registers ----
    float Xs[8];
#pragma unroll
    for (int b = 0; b < 8; ++b) {
        float sb = 0.f;
#pragma unroll
        for (int t = 0; t < 4; ++t)
            if (lane + 64 * t < NN / 4)
                sb += (v[t][b].x + v[t][b].y) + (v[t][b].z + v[t][b].w);
        Xs[b] = wave_sum(sb);
    }
    const float S = ((Xs[0] + Xs[1]) + (Xs[2] + Xs[3])) +
                    ((Xs[4] + Xs[5]) + (Xs[6] + Xs[7]));

    // ---- Wave-uniform constant algebra ----
    float alpha[2];
#pragma unroll
    for (int f = 0; f < 2; ++f) {
        float a = 0.f;
#pragma unroll
        for (int e = 0; e < 4; ++e) a += W1[e] * Wf1e[(2 * e) * 2 + f];
        alpha[f] = (float)NN * a;
    }
    float gamma[3];
#pragma unroll
    for (int vv = 0; vv < 3; ++vv) {
        float g = 0.f;
#pragma unroll
        for (int f = 0; f < 2; ++f) g += alpha[f] * Wf1v[f * 3 + vv];
        gamma[vv] = g;
    }
    float uA[6], cB[6], vAc[6];
#pragma unroll
    for (int m = 0; m < 2; ++m)
#pragma unroll
        for (int k = 0; k < 3; ++k) {
            float ua = 0.f, ub = 0.f, va = 0.f, vb = 0.f;
#pragma unroll
            for (int e = 0; e < 4; ++e) {
                float wE = Wfk[k * 16 + (2 * e) * 2 + m];
                float wO = Wfk[k * 16 + (2 * e + 1) * 2 + m];
                ua += W2[e] * wE; ub += b2[e] * wE;
                va += W2[e] * wO; vb += b2[e] * wO;
            }
            uA[m * 3 + k]  = ua;
            cB[m * 3 + k]  = ub + vb + bfk[k * 2 + m];
            vAc[m * 3 + k] = va;
        }
    float Bsum[2];
#pragma unroll
    for (int f = 0; f < 2; ++f) {
        float t0 = 0.f, t1 = 0.f;
#pragma unroll
        for (int e = 0; e < 4; ++e) {
            t0 += b1[e] * Wf1e[(2 * e) * 2 + f];
            t1 += (S * W1[e] + 8.f * (float)NN * b1[e]) * Wf1e[(2 * e + 1) * 2 + f];
        }
        Bsum[f] = 8.f * (float)NN * t0 + t1 + 8.f * (float)NN * bf1e[f];
    }
    float Ds[3];
#pragma unroll
    for (int vv = 0; vv < 3; ++vv) {
        float d = 8.f * bf1v[vv];
#pragma unroll
        for (int f = 0; f < 2; ++f) d += Bsum[f] * Wf1v[f * 3 + vv];
        Ds[vv] = d;
    }
    // edge_logits[i,j,k] (scaled by log2e for base-2 softmax) = AiQ[k] + PB[k]*Xs_j
    const float LOG2E = 1.4426950408889634f;
    float PB[3], AiQ[3];
    {
        float xsi = 0.f;
#pragma unroll
        for (int b = 0; b < 8; ++b) xsi += x[b * NN + i];
#pragma unroll
        for (int k = 0; k < 3; ++k) {
            float PA = 0.f, QA = 0.f, pb = 0.f, qb = 0.f;
#pragma unroll
            for (int vv = 0; vv < 3; ++vv) {
                PA += gamma[vv] * Wf2e[(2 * vv) * 3 + k];
                QA += Ds[vv]    * Wf2e[(2 * vv) * 3 + k];
                pb += gamma[vv] * Wf2e[(2 * vv + 1) * 3 + k];
                qb += Ds[vv]    * Wf2e[(2 * vv + 1) * 3 + k];
            }
            PB[k]  = pb * LOG2E;
            AiQ[k] = (PA * xsi + QA + bf2e[k] + qb) * LOG2E;
        }
    }

    // ---- Softmax + weighted sums (k=0,1 only; k=2 derived), register-resident ----
    const float ai0 = AiQ[0], ai1 = AiQ[1], ai2 = AiQ[2];
    const float pb0 = PB[0], pb1 = PB[1], pb2 = PB[2];
    float Q0 = 0.f, Q1 = 0.f;
    float R[8][2];
#pragma unroll
    for (int b = 0; b < 8; ++b) { R[b][0] = 0.f; R[b][1] = 0.f; }

#pragma unroll
    for (int t = 0; t < 4; ++t) {
        if (lane + 64 * t < NN / 4) {
            const float* vf = reinterpret_cast<const float*>(v[t]);
#pragma unroll
            for (int u = 0; u < 4; ++u) {
                float xs = 0.f;
#pragma unroll
                for (int b = 0; b < 8; ++b) xs += vf[b * 4 + u];
                float l0 = ai0 + pb0 * xs, l1 = ai1 + pb1 * xs, l2 = ai2 + pb2 * xs;
                float mx = fmaxf(l0, fmaxf(l1, l2));
                float e0 = exp2f(l0 - mx), e1 = exp2f(l1 - mx), e2 = exp2f(l2 - mx);
                float inv = 1.f / (e0 + e1 + e2);
                float p0 = e0 * inv, p1 = e1 * inv;
                Q0 += p0; Q1 += p1;
#pragma unroll
                for (int b = 0; b < 8; ++b) {
                    float xb = vf[b * 4 + u];
                    R[b][0] += p0 * xb;
                    R[b][1] += p1 * xb;
                }
            }
        }
    }

    Q0 = wave_sum(Q0); Q1 = wave_sum(Q1);
#pragma unroll
    for (int b = 0; b < 8; ++b) {
        R[b][0] = wave_sum(R[b][0]);
        R[b][1] = wave_sum(R[b][1]);
    }

    // ---- Epilogue: lanes 0..7 each write one batch row ----
    if (lane < 8) {
        const int b = lane;
        float xi = x[b * NN + i];
        float Q2 = (float)NN - Q0 - Q1;
        float Rk0 = R[b][0], Rk1 = R[b][1];
        float Rk2 = Xs[b] - Rk0 - Rk1;
        float ve[2];
#pragma unroll
        for (int m = 0; m < 2; ++m) {
            ve[m] = Q0 * (uA[m * 3 + 0] * xi + cB[m * 3 + 0]) + vAc[m * 3 + 0] * Rk0
                  + Q1 * (uA[m * 3 + 1] * xi + cB[m * 3 + 1]) + vAc[m * 3 + 1] * Rk1
                  + Q2 * (uA[m * 3 + 2] * xi + cB[m * 3 + 2]) + vAc[m * 3 + 2] * Rk2;
        }
        out[b * NN + i] = xi + ve[0] * Wf2v[0] + ve[1] * Wf2v[1] + xi * Wf2v[2] + bf2v[0];
    }
}

extern "C" void kernel_launch(void* const* d_in, const int* in_sizes, int n_in,
                              void* d_out, int out_size, void* d_ws, size_t ws_size,
                              hipStream_t stream) {
    const float* x    = (const float*)d_in[0];
    const float* W1   = (const float*)d_in[1];
    const float* b1   = (const float*)d_in[2];
    const float* W2   = (const float*)d_in[3];
    const float* b2   = (const float*)d_in[4];
    const float* Wf1e = (const float*)d_in[5];
    const float* bf1e = (const float*)d_in[6];
    const float* Wf2e = (const float*)d_in[7];
    const float* bf2e = (const float*)d_in[8];
    const float* Wfk  = (const float*)d_in[9];
    const float* bfk  = (const float*)d_in[10];
    const float* Wf1v = (const float*)d_in[11];
    const float* bf1v = (const float*)d_in[12];
    const float* Wf2v = (const float*)d_in[13];
    const float* bf2v = (const float*)d_in[14];

    fused_kernel<<<NN / 4, 256, 0, stream>>>(x, W1, b1, W2, b2, Wf1e, bf1e,
                                             Wf2e, bf2e, Wfk, bfk, Wf1v, bf1v,
                                             Wf2v, bf2v, (float*)d_out);
}